// Round 2
// baseline (215.307 us; speedup 1.0000x reference)
//
#include <hip/hip_runtime.h>

#define BB 2
#define CC 64
#define HH 128
#define WW 128
#define NN (HH*WW)          // 16384 queries per batch
#define MM ((HH/2)*(WW/2))  // 4096 keys per batch
#define CV 32

typedef __attribute__((ext_vector_type(8))) short bf16x8;
typedef __attribute__((ext_vector_type(4))) float f32x4;
typedef unsigned int uint32;

union U8 { bf16x8 v; uint32 u[4]; };

__device__ __forceinline__ short f2bf(float f) {
    union { float f; unsigned u; } v; v.f = f;
    unsigned u = v.u + 0x7fffu + ((v.u >> 16) & 1u);   // RNE
    return (short)(u >> 16);
}
__device__ __forceinline__ uint32 pack2bf(float lo, float hi) {
    return (uint32)(unsigned short)f2bf(lo) | ((uint32)(unsigned short)f2bf(hi) << 16);
}
// truncation pack: 3 ops; downward bias cancels in softmax ratio P/l
__device__ __forceinline__ uint32 pack2bf_trunc(float lo, float hi) {
    union { float f; uint32 u; } a, b; a.f = lo; b.f = hi;
    return (a.u >> 16) | (b.u & 0xffff0000u);
}

// ---------------------------------------------------------------------------
// Kernel 1: conv1x1 projections + 2x2 maxpool. z=0: theta+phi, z=1: g.
// Grid (64, B, 2) x 256 threads; block = 2 image rows.
// Outputs: Qb [B][N][8] bf16, Kb [B][M][8] bf16, Vt [B][32][M] bf16.
// ---------------------------------------------------------------------------
__global__ __launch_bounds__(256) void proj_kernel(
    const float* __restrict__ x, const float* __restrict__ wt,
    const float* __restrict__ wp, const float* __restrict__ wg,
    short* __restrict__ Qb, short* __restrict__ Kb, short* __restrict__ Vt)
{
    __shared__ float w_lds[2048];
    __shared__ float pg_lds[256][33];   // +1 pad: conflict-free writes
    int tid = threadIdx.x, z = blockIdx.z;
    if (z == 0) { for (int i = tid; i < 1024; i += 256) w_lds[i] = (i < 512) ? wt[i] : wp[i-512]; }
    else        { for (int i = tid; i < 2048; i += 256) w_lds[i] = wg[i]; }
    __syncthreads();

    int s = blockIdx.x, b = blockIdx.y;
    int r = tid >> 7, wc = tid & 127;
    int n = (2*s + r)*WW + wc;

    float xv[64];
    #pragma unroll
    for (int c = 0; c < 64; ++c) xv[c] = x[((b*CC + c) << 14) + n];

    if (z == 0) {
        float o8[8];
        #pragma unroll
        for (int o = 0; o < 8; ++o) {
            float a = 0.f;
            #pragma unroll
            for (int c = 0; c < 64; ++c) a += w_lds[o*64 + c]*xv[c];
            o8[o] = a;
        }
        uint4 val;
        val.x = pack2bf(o8[0], o8[1]); val.y = pack2bf(o8[2], o8[3]);
        val.z = pack2bf(o8[4], o8[5]); val.w = pack2bf(o8[6], o8[7]);
        ((uint4*)Qb)[b*NN + n] = val;
        #pragma unroll
        for (int o = 0; o < 8; ++o) {
            float a = 0.f;
            #pragma unroll
            for (int c = 0; c < 64; ++c) a += w_lds[512 + o*64 + c]*xv[c];
            pg_lds[tid][o] = a;
        }
        __syncthreads();
        if (tid < 64) {
            int w2 = tid, t00 = 2*w2, t01 = t00+1, t10 = 128+2*w2, t11 = t10+1;
            int m = s*64 + w2;
            float kf[8];
            #pragma unroll
            for (int o = 0; o < 8; ++o)
                kf[o] = fmaxf(fmaxf(pg_lds[t00][o], pg_lds[t01][o]),
                              fmaxf(pg_lds[t10][o], pg_lds[t11][o]));
            uint4 val2;
            val2.x = pack2bf(kf[0], kf[1]); val2.y = pack2bf(kf[2], kf[3]);
            val2.z = pack2bf(kf[4], kf[5]); val2.w = pack2bf(kf[6], kf[7]);
            ((uint4*)Kb)[b*MM + m] = val2;
        }
    } else {
        #pragma unroll
        for (int o = 0; o < 32; ++o) {
            float a = 0.f;
            #pragma unroll
            for (int c = 0; c < 64; ++c) a += w_lds[o*64 + c]*xv[c];
            pg_lds[tid][o] = a;
        }
        __syncthreads();
        int g = tid >> 6, w2 = tid & 63;
        int t00 = 2*w2, t01 = t00+1, t10 = 128+2*w2, t11 = t10+1;
        int m = s*64 + w2;
        #pragma unroll
        for (int j = 0; j < 8; ++j) {
            int o = g*8 + j;
            float a = fmaxf(fmaxf(pg_lds[t00][o], pg_lds[t01][o]),
                            fmaxf(pg_lds[t10][o], pg_lds[t11][o]));
            Vt[(b*CV + o)*MM + m] = f2bf(a);
        }
    }
}

// ---------------------------------------------------------------------------
// Kernel 2: fully fused attention + normalize + w_o + residual.
// Wave = one 16-query tile, sweeps all 4096 keys. Transposed scores
// S'[key][q] so P's C-layout is directly the PV MFMA B-operand (V A-frag
// loaded with matching key permutation). No LDS, no atomics, no split-K.
// Grid = B*N/(16*4) = 512 blocks x 256 threads.
// ---------------------------------------------------------------------------
__global__ __launch_bounds__(256, 2) void attn_kernel(
    const short* __restrict__ Qb, const short* __restrict__ Kb,
    const short* __restrict__ Vt, const float* __restrict__ x,
    const float* __restrict__ wo, const float* __restrict__ gamma,
    float* __restrict__ out)
{
    int tid = threadIdx.x, wave = tid >> 6, lane = tid & 63;
    int quad = lane >> 4, c15 = lane & 15;
    int gq = blockIdx.x*4 + wave;           // global q-tile id
    int b = gq >> 10;                        // 1024 q-tiles per batch
    int qbase = (gq & 1023) << 4;

    const f32x4 zero4 = {0.f, 0.f, 0.f, 0.f};
    bf16x8 zero8 = (bf16x8)0;

    // Q as B-operand of score MFMA: B[k=ch][n=q], quad0 holds ch 0..7
    bf16x8 bq = (quad == 0) ? ((const bf16x8*)Qb)[b*NN + qbase + c15] : zero8;

    const short* Kbb = Kb + b*MM*8;
    const short* V0b = Vt + (b*CV + c15)*MM;        // ch = c15
    const short* V1b = Vt + (b*CV + 16 + c15)*MM;   // ch = 16 + c15

    f32x4 D0 = zero4, D1 = zero4;
    float l_part = 0.f;

    // prefetch superchunk 0 (32 keys)
    bf16x8 kf0 = zero8, kf1 = zero8;
    if (quad == 0) {
        kf0 = *(const bf16x8*)(Kbb + c15*8);
        kf1 = *(const bf16x8*)(Kbb + (16 + c15)*8);
    }
    uint2 v00 = *(const uint2*)(V0b + quad*4);
    uint2 v01 = *(const uint2*)(V0b + 16 + quad*4);
    uint2 v10 = *(const uint2*)(V1b + quad*4);
    uint2 v11 = *(const uint2*)(V1b + 16 + quad*4);

    #pragma unroll 2
    for (int sc = 0; sc < 128; ++sc) {
        bf16x8 nk0 = zero8, nk1 = zero8;
        uint2 nv00 = v00, nv01 = v01, nv10 = v10, nv11 = v11;
        if (sc < 127) {
            int k0 = (sc + 1)*32;
            if (quad == 0) {
                nk0 = *(const bf16x8*)(Kbb + (k0 + c15)*8);
                nk1 = *(const bf16x8*)(Kbb + (k0 + 16 + c15)*8);
            }
            nv00 = *(const uint2*)(V0b + k0 + quad*4);
            nv01 = *(const uint2*)(V0b + k0 + 16 + quad*4);
            nv10 = *(const uint2*)(V1b + k0 + quad*4);
            nv11 = *(const uint2*)(V1b + k0 + 16 + quad*4);
        }
        // S'[key][q]: C row = key = quad*4+r, col = q = c15
        f32x4 s0 = __builtin_amdgcn_mfma_f32_16x16x32_bf16(kf0, bq, zero4, 0, 0, 0);
        f32x4 s1 = __builtin_amdgcn_mfma_f32_16x16x32_bf16(kf1, bq, zero4, 0, 0, 0);
        float p00 = __expf(s0[0]), p01 = __expf(s0[1]), p02 = __expf(s0[2]), p03 = __expf(s0[3]);
        float p10 = __expf(s1[0]), p11 = __expf(s1[1]), p12 = __expf(s1[2]), p13 = __expf(s1[3]);
        l_part += ((p00 + p01) + (p02 + p03)) + ((p10 + p11) + (p12 + p13));
        // P C-frags -> PV B-operand (keys at position (quad,j):
        //   j<4: k0+quad*4+j,  j>=4: k0+16+quad*4+(j-4))
        U8 bp;
        bp.u[0] = pack2bf_trunc(p00, p01); bp.u[1] = pack2bf_trunc(p02, p03);
        bp.u[2] = pack2bf_trunc(p10, p11); bp.u[3] = pack2bf_trunc(p12, p13);
        // V A-frags with the SAME key permutation
        U8 av0, av1;
        av0.u[0] = v00.x; av0.u[1] = v00.y; av0.u[2] = v01.x; av0.u[3] = v01.y;
        av1.u[0] = v10.x; av1.u[1] = v10.y; av1.u[2] = v11.x; av1.u[3] = v11.y;
        D0 = __builtin_amdgcn_mfma_f32_16x16x32_bf16(av0.v, bp.v, D0, 0, 0, 0);
        D1 = __builtin_amdgcn_mfma_f32_16x16x32_bf16(av1.v, bp.v, D1, 0, 0, 0);
        kf0 = nk0; kf1 = nk1;
        v00 = nv00; v01 = nv01; v10 = nv10; v11 = nv11;
    }

    // l across quads (lanes c15, c15+16, c15+32, c15+48)
    float l = l_part;
    l += __shfl_xor(l, 16);
    l += __shfl_xor(l, 32);
    float rl = 1.0f / l;

    // y = D*rl in C-layout == B-operand of w_o MFMA (ch_eff(quad,j) =
    // j<4 ? quad*4+j : 16+quad*4+(j-4))
    U8 By;
    By.u[0] = pack2bf(D0[0]*rl, D0[1]*rl); By.u[1] = pack2bf(D0[2]*rl, D0[3]*rl);
    By.u[2] = pack2bf(D1[0]*rl, D1[1]*rl); By.u[3] = pack2bf(D1[2]*rl, D1[3]*rl);

    float gam = gamma[0];
    #pragma unroll
    for (int t = 0; t < 4; ++t) {
        int co = t*16 + c15;   // A row this lane loads
        float4 wlo = *(const float4*)(wo + co*32 + quad*4);
        float4 whi = *(const float4*)(wo + co*32 + 16 + quad*4);
        U8 aw;
        aw.u[0] = pack2bf(wlo.x, wlo.y); aw.u[1] = pack2bf(wlo.z, wlo.w);
        aw.u[2] = pack2bf(whi.x, whi.y); aw.u[3] = pack2bf(whi.z, whi.w);
        f32x4 o2 = __builtin_amdgcn_mfma_f32_16x16x32_bf16(aw.v, By.v, zero4, 0, 0, 0);
        #pragma unroll
        for (int r2 = 0; r2 < 4; ++r2) {
            int co_r = t*16 + quad*4 + r2;          // D row = co
            int idx = ((b*CC + co_r) << 14) + qbase + c15;
            out[idx] = x[idx] + gam*o2[r2];
        }
    }
}

// ---------------------------------------------------------------------------
// Workspace: Qb 512K @ 0, Kb 128K @ 524288, Vt 512K @ 655360. No zeroing.
// ---------------------------------------------------------------------------
extern "C" void kernel_launch(void* const* d_in, const int* in_sizes, int n_in,
                              void* d_out, int out_size, void* d_ws, size_t ws_size,
                              hipStream_t stream) {
    const float* x     = (const float*)d_in[0];
    const float* wt    = (const float*)d_in[1];
    const float* wp    = (const float*)d_in[2];
    const float* wg    = (const float*)d_in[3];
    const float* wo    = (const float*)d_in[4];
    const float* gamma = (const float*)d_in[5];
    float* out = (float*)d_out;

    char* ws = (char*)d_ws;
    short* Qb = (short*)(ws);
    short* Kb = (short*)(ws + 524288);
    short* Vt = (short*)(ws + 655360);

    dim3 g1(HH/2, BB, 2);
    proj_kernel<<<g1, 256, 0, stream>>>(x, wt, wp, wg, Qb, Kb, Vt);
    attn_kernel<<<BB*NN/64, 256, 0, stream>>>(Qb, Kb, Vt, x, wo, gamma, out);
}